// Round 2
// baseline (819.679 us; speedup 1.0000x reference)
//
#include <hip/hip_runtime.h>

#define B 32
#define F 1024
#define S 2048
#define KTOP 16
#define NB 32                     /* row-bands per batch */
#define ROWS_PER_BAND (S / NB)    /* 64 */

// Kernel A: partial column sums. Each block streams a CONTIGUOUS 512 KiB band:
// 512 threads x float4 = one full 8 KiB row per iteration, 64 sequential rows.
// Pure-memcpy access pattern -> should pin HBM BW.
__global__ void __launch_bounds__(512) colsum_band(const float* __restrict__ w,
                                                   float* __restrict__ partial) {
    int band = blockIdx.x % NB;
    int b = blockIdx.x / NB;
    int col = threadIdx.x * 4;
    const float* p = w + (size_t)b * S * S + (size_t)band * ROWS_PER_BAND * S + col;
    float4 acc = make_float4(0.f, 0.f, 0.f, 0.f);
#pragma unroll 8
    for (int i = 0; i < ROWS_PER_BAND; ++i) {
        float4 v = *(const float4*)(p + (size_t)i * S);
        acc.x += v.x; acc.y += v.y; acc.z += v.z; acc.w += v.w;
    }
    *(float4*)(partial + (size_t)(b * NB + band) * S + col) = acc;
}

// Kernel B: fold NB partials -> column sums in LDS, then top-16 per batch
// (descending, ties -> lower index, lax.top_k semantics). One block per batch.
__global__ void __launch_bounds__(256) reduce_topk(const float* __restrict__ partial,
                                                   int* __restrict__ idx) {
    __shared__ float vals[S];
    __shared__ float rv[256];
    __shared__ int ri[256];
    int b = blockIdx.x;
    int tid = threadIdx.x;
    for (int s = tid; s < S; s += 256) {
        float acc = 0.f;
#pragma unroll
        for (int nb = 0; nb < NB; ++nb) acc += partial[(size_t)(b * NB + nb) * S + s];
        vals[s] = acc;
    }
    __syncthreads();
    for (int k = 0; k < KTOP; ++k) {
        float bv = -1e30f;
        int bi = 0x7fffffff;
        for (int s = tid; s < S; s += 256) {
            float v = vals[s];
            if (v > bv) { bv = v; bi = s; } // strict > keeps smallest index per thread
        }
        rv[tid] = bv; ri[tid] = bi;
        __syncthreads();
        for (int off = 128; off > 0; off >>= 1) {
            if (tid < off) {
                float ov = rv[tid + off]; int oi = ri[tid + off];
                if (ov > rv[tid] || (ov == rv[tid] && oi < ri[tid])) { rv[tid] = ov; ri[tid] = oi; }
            }
            __syncthreads();
        }
        if (tid == 0) {
            idx[b * KTOP + k] = ri[0];
            vals[ri[0]] = -1e30f;
        }
        __syncthreads();
    }
}

// Kernel C: out[b][f][k] = x[b][f][idx[b][k]]. Coalesced 1 KiB/wave writes;
// scattered 64B-line reads spread across all CUs.
__global__ void __launch_bounds__(256) gather_kernel(const float* __restrict__ x,
                                                     const int* __restrict__ idx,
                                                     float* __restrict__ out) {
    __shared__ int sidx[KTOP];
    int t = blockIdx.x * blockDim.x + threadIdx.x; // 0 .. B*F*KTOP-1
    int b = t / (KTOP * F);
    if (threadIdx.x < KTOP) sidx[threadIdx.x] = idx[b * KTOP + threadIdx.x];
    __syncthreads();
    int k = t % KTOP;
    int f = (t / KTOP) % F;
    out[t] = x[((size_t)b * F + f) * S + sidx[k]];
}

extern "C" void kernel_launch(void* const* d_in, const int* in_sizes, int n_in,
                              void* d_out, int out_size, void* d_ws, size_t ws_size,
                              hipStream_t stream) {
    const float* x = (const float*)d_in[0];
    const float* w = (const float*)d_in[1];
    float* out = (float*)d_out;

    float* partial = (float*)d_ws;                  // B*NB*S floats = 8 MiB
    int* idx = (int*)(partial + (size_t)B * NB * S); // B*KTOP ints

    colsum_band<<<B * NB, 512, 0, stream>>>(w, partial);
    reduce_topk<<<B, 256, 0, stream>>>(partial, idx);
    gather_kernel<<<(B * F * KTOP) / 256, 256, 0, stream>>>(x, idx, out);
}